// Round 2
// baseline (165.361 us; speedup 1.0000x reference)
//
#include <hip/hip_runtime.h>
#include <type_traits>

typedef __bf16 bf16;
typedef __bf16 bf16x8 __attribute__((ext_vector_type(8)));
typedef __bf16 bf16x4 __attribute__((ext_vector_type(4)));
typedef float floatx4 __attribute__((ext_vector_type(4)));

#define SEQ 4096
#define DM 1024
#define NH 16
#define HD 64
#define GUARD 64

__device__ __forceinline__ floatx4 mfma32(bf16x8 a, bf16x8 b, floatx4 c) {
    return __builtin_amdgcn_mfma_f32_16x16x32_bf16(a, b, c, 0, 0, 0);
}

__device__ __forceinline__ bf16x8 load8(const bf16* p) {
    return *(const bf16x8*)p;
}

__device__ __forceinline__ void async_ld16(const bf16* g, bf16* l) {
    __builtin_amdgcn_global_load_lds(
        (const __attribute__((address_space(1))) unsigned int*)g,
        (__attribute__((address_space(3))) unsigned int*)l,
        16, 0, 0);
}

// fused prep: cast x, Wq,Wk,Wv,Wo to bf16; concat biases to fp32 bcat.
__global__ __launch_bounds__(256) void prep_kernel(
    const float* __restrict__ x,  const float* __restrict__ Wq,
    const float* __restrict__ Wk, const float* __restrict__ Wv,
    const float* __restrict__ Wo, const float* __restrict__ bq,
    const float* __restrict__ bk, const float* __restrict__ bv,
    bf16* __restrict__ xb, bf16* __restrict__ Wcat,
    bf16* __restrict__ Wob, float* __restrict__ bcat)
{
    const int WN8 = 131072;           // (1024*1024)/8
    const int XN8 = 524288;           // (4096*1024)/8
    int b = blockIdx.x;
    if (b == 4096) {
        for (int k = threadIdx.x; k < 3 * DM; k += 256)
            bcat[k] = k < DM ? bq[k] : (k < 2 * DM ? bk[k - DM] : bv[k - 2 * DM]);
        return;
    }
    int c = b * 256 + threadIdx.x;
    const float* src; bf16* dst;
    if (c < XN8)              { src = x;  dst = xb; }
    else if (c < XN8 + WN8)   { src = Wq; dst = Wcat;                 c -= XN8; }
    else if (c < XN8 + 2*WN8) { src = Wk; dst = Wcat + (size_t)DM*DM;     c -= XN8 + WN8; }
    else if (c < XN8 + 3*WN8) { src = Wv; dst = Wcat + (size_t)2*DM*DM;   c -= XN8 + 2*WN8; }
    else                      { src = Wo; dst = Wob;                  c -= XN8 + 3*WN8; }
    float4 a = ((const float4*)src)[2 * c], d2 = ((const float4*)src)[2 * c + 1];
    bf16x8 o;
    o[0] = (bf16)a.x;  o[1] = (bf16)a.y;  o[2] = (bf16)a.z;  o[3] = (bf16)a.w;
    o[4] = (bf16)d2.x; o[5] = (bf16)d2.y; o[6] = (bf16)d2.z; o[7] = (bf16)d2.w;
    *(bf16x8*)(dst + 8 * (size_t)c) = o;
}

// ---- QKV projection GEMM: [4096,1024] @ [3072,1024]^T, head-major outputs.
// BM=128, BN=128, BK=64, XOR-swizzled LDS (0 bank conflicts, verified r6).
// launch_bounds(256,3): cap regs at 170 so 3 blocks/CU are resident.
// r7: XCD-aware 2D block remap (neutral measured r1; kept, theory-sound).
__global__ __launch_bounds__(256, 3) void gemm_qkv_kernel(
    const bf16* __restrict__ A,      // xb [4096][1024]
    const bf16* __restrict__ B,      // Wcat [3072][1024]
    const float* __restrict__ bias,  // bcat [3072]
    bf16* __restrict__ Qh, bf16* __restrict__ Kh, bf16* __restrict__ Vt)
{
    constexpr int K = DM;
    __shared__ bf16 As[128 * 64];
    __shared__ bf16 Bs[128 * 64];

    const int tid  = threadIdx.x;
    const int wave = tid >> 6;
    const int lane = tid & 63;
    const int l15  = lane & 15;
    const int quad = lane >> 4;
    // r7 remap: lid reconstructs hw dispatch order (x fastest); XCD=lid&7.
    const int lid = blockIdx.y * 32 + blockIdx.x;
    const int xcd = lid & 7;
    const int rr  = lid >> 3;                   // 0..95
    const int m0 = ((xcd & 3) * 8 + (rr & 7)) * 128;
    const int n0 = ((xcd >> 2) * 12 + (rr >> 3)) * 128;
    const int wm = (wave & 1) * 64;
    const int wn = (wave >> 1) * 64;

    // staging: chunk = 8 rows x 64 cols (1024B). lane -> (row lane>>3,
    // LDS slot lane&7); global col chunk gc = (slot - row)&7  [XOR swizzle]
    const int lr = lane >> 3;
    const int gc = ((lane & 7) - lr) & 7;

    const bf16* aptr[4]; bf16* alds[4];
    const bf16* bptr[4]; bf16* blds[4];
#pragma unroll
    for (int i = 0; i < 4; ++i) {
        int ci = wave + 4 * i;
        aptr[i] = A + (size_t)(m0 + ci * 8 + lr) * K + gc * 8;
        alds[i] = As + ci * 512;
        bptr[i] = B + (size_t)(n0 + ci * 8 + lr) * K + gc * 8;
        blds[i] = Bs + ci * 512;
    }

    floatx4 acc[4][4] = {};
    const int sw0 = (quad + (l15 & 7)) & 7;   // swizzle base for frag reads
    const bool qk = (n0 < 2 * DM);

    auto kloop = [&](auto swtag) {
        constexpr bool SW = decltype(swtag)::value;
        for (int k0 = 0; k0 < K; k0 += 64) {
            __syncthreads();
#pragma unroll
            for (int i = 0; i < 4; ++i) async_ld16(aptr[i] + k0, alds[i]);
#pragma unroll
            for (int i = 0; i < 4; ++i) async_ld16(bptr[i] + k0, blds[i]);
            __syncthreads();
#pragma unroll
            for (int h = 0; h < 2; ++h) {
                const int so = ((sw0 + 4 * h) & 7) * 8;
                bf16x8 af[4], bfr[4];
#pragma unroll
                for (int i = 0; i < 4; ++i)
                    af[i] = load8(As + (wm + i * 16 + l15) * 64 + so);
#pragma unroll
                for (int j = 0; j < 4; ++j)
                    bfr[j] = load8(Bs + (wn + j * 16 + l15) * 64 + so);
#pragma unroll
                for (int i = 0; i < 4; ++i)
#pragma unroll
                    for (int j = 0; j < 4; ++j)
                        acc[i][j] = SW ? mfma32(bfr[j], af[i], acc[i][j])
                                       : mfma32(af[i], bfr[j], acc[i][j]);
            }
        }
    };
    if (qk) kloop(std::true_type{}); else kloop(std::false_type{});

    const int nb = n0 + wn;   // multiple of 64
    if (qk) {
        // swapped: lane holds 4 consecutive out-cols (head dims) for row s
        bf16* dst = (nb < DM) ? Qh : Kh;
        const int hh = ((nb < DM) ? nb : nb - DM) >> 6;
#pragma unroll
        for (int i = 0; i < 4; ++i) {
            int s = m0 + wm + i * 16 + l15;
            bf16* row = dst + ((size_t)hh * SEQ + s) * 64;
#pragma unroll
            for (int j = 0; j < 4; ++j) {
                int d4 = j * 16 + quad * 4;
                float4 bv = *(const float4*)(bias + nb + d4);
                bf16x4 o = {(bf16)(acc[i][j][0] + bv.x), (bf16)(acc[i][j][1] + bv.y),
                            (bf16)(acc[i][j][2] + bv.z), (bf16)(acc[i][j][3] + bv.w)};
                *(bf16x4*)(row + d4) = o;
            }
        }
    } else {
        // non-swapped: lane holds 4 consecutive s for out-col -> V^T rows
#pragma unroll
        for (int j = 0; j < 4; ++j) {
            int vrow = (nb - 2 * DM) + j * 16 + l15;     // h*64+d, 0..1023
            float bvs = bias[nb + j * 16 + l15];
            bf16* row = Vt + (size_t)vrow * SEQ;
#pragma unroll
            for (int i = 0; i < 4; ++i) {
                int s4 = m0 + wm + i * 16 + quad * 4;
                bf16x4 o = {(bf16)(acc[i][j][0] + bvs), (bf16)(acc[i][j][1] + bvs),
                            (bf16)(acc[i][j][2] + bvs), (bf16)(acc[i][j][3] + bvs)};
                *(bf16x4*)(row + s4) = o;
            }
        }
    }
}

// ---- out-projection GEMM, r8: full 128x128 m97-structure (clone of the
// verified gemm_qkv k-loop, swapped MFMA) replacing the BM=64 tile whose
// 2x4-acc waves had MFMA:ds_read = 16:12 per K-step (~350-450 TF class).
// 128x128 gives 32:16 (~600-700 TF even at 1 block/CU). Grid (32,8)=256.
// Epilogue: swapped mapping -> lane holds 4 consecutive out-cols for row
// xm (same mapping as gemm_qkv qk-path / old gemm_sw), fp32+bias float4.
__global__ __launch_bounds__(256, 3) void gemm_out_kernel(
    const bf16* __restrict__ A,      // ctx [4096][1024]
    const bf16* __restrict__ B,      // Wob [1024][1024]
    const float* __restrict__ bias,  // bo [1024]
    float* __restrict__ C)           // out [4096][1024] fp32
{
    constexpr int K = DM;
    constexpr int N = DM;
    __shared__ bf16 As[128 * 64];
    __shared__ bf16 Bs[128 * 64];

    const int tid  = threadIdx.x;
    const int wave = tid >> 6;
    const int lane = tid & 63;
    const int l15  = lane & 15;
    const int quad = lane >> 4;
    const int m0 = blockIdx.x * 128;
    const int n0 = blockIdx.y * 128;
    const int wm = (wave & 1) * 64;
    const int wn = (wave >> 1) * 64;

    const int lr = lane >> 3;
    const int gc = ((lane & 7) - lr) & 7;

    const bf16* aptr[4]; bf16* alds[4];
    const bf16* bptr[4]; bf16* blds[4];
#pragma unroll
    for (int i = 0; i < 4; ++i) {
        int ci = wave + 4 * i;
        aptr[i] = A + (size_t)(m0 + ci * 8 + lr) * K + gc * 8;
        alds[i] = As + ci * 512;
        bptr[i] = B + (size_t)(n0 + ci * 8 + lr) * K + gc * 8;
        blds[i] = Bs + ci * 512;
    }

    floatx4 acc[4][4] = {};
    const int sw0 = (quad + (l15 & 7)) & 7;

    for (int k0 = 0; k0 < K; k0 += 64) {
        __syncthreads();
#pragma unroll
        for (int i = 0; i < 4; ++i) async_ld16(aptr[i] + k0, alds[i]);
#pragma unroll
        for (int i = 0; i < 4; ++i) async_ld16(bptr[i] + k0, blds[i]);
        __syncthreads();
#pragma unroll
        for (int h = 0; h < 2; ++h) {
            const int so = ((sw0 + 4 * h) & 7) * 8;
            bf16x8 af[4], bfr[4];
#pragma unroll
            for (int i = 0; i < 4; ++i)
                af[i] = load8(As + (wm + i * 16 + l15) * 64 + so);
#pragma unroll
            for (int j = 0; j < 4; ++j)
                bfr[j] = load8(Bs + (wn + j * 16 + l15) * 64 + so);
#pragma unroll
            for (int i = 0; i < 4; ++i)
#pragma unroll
                for (int j = 0; j < 4; ++j)
                    acc[i][j] = mfma32(bfr[j], af[i], acc[i][j]);
        }
    }

#pragma unroll
    for (int i = 0; i < 4; ++i) {
        int xm = m0 + wm + i * 16 + l15;
#pragma unroll
        for (int j = 0; j < 4; ++j) {
            int cn = n0 + wn + j * 16 + quad * 4;
            float4 bv = *(const float4*)(bias + cn);
            float4 o = {acc[i][j][0] + bv.x, acc[i][j][1] + bv.y,
                        acc[i][j][2] + bv.z, acc[i][j][3] + bv.w};
            *(float4*)(C + (size_t)xm * N + cn) = o;
        }
    }
}

// ---- sliding-window attention, head-major inputs, zero barriers.
// Qh,Kh: [h][s][64]; Vt: [h*64+d][SEQ] (base has 64-elem guard each side).
// r7: XCD remap (2 heads/XCD), V-frag prefetch, setprio around PV MFMA.
// All neutral measured (r1) but theory-sound; kept.
__global__ __launch_bounds__(256) void swattn_kernel(
    const bf16* __restrict__ Qh, const bf16* __restrict__ Kh,
    const bf16* __restrict__ Vt, bf16* __restrict__ ctx)
{
    __shared__ bf16 Pc[4][16][40];
    __shared__ float lred[4][16];

    const int tid  = threadIdx.x;
    const int wave = tid >> 6;
    const int lane = tid & 63;
    const int l15  = lane & 15;
    const int quad = lane >> 4;
    // r7: bijective remap, hw linear order lid = y*64+x, XCD = lid&7.
    const int lid  = blockIdx.y * 64 + blockIdx.x;
    const int swz  = (lid & 7) * 128 + (lid >> 3);
    const int q0   = (swz & 63) * 64;
    const int h    = swz >> 6;
    const int hoff = h * HD;

    const bf16* qhead = Qh + (size_t)h * SEQ * 64;
    const bf16* khead = Kh + (size_t)h * SEQ * 64;
    const bf16* vhead = Vt + (size_t)hoff * SEQ;

    const int qrow = q0 + wave * 16 + l15;
    bf16x8 aq0 = load8(qhead + (size_t)qrow * 64 + quad * 8);
    bf16x8 aq1 = load8(qhead + (size_t)qrow * 64 + quad * 8 + 32);

    const int ws = q0 - 64 + wave * 16;   // wave window start (global key)
    floatx4 s[9];
#pragma unroll
    for (int st = 0; st < 9; ++st) {
        int kr = ws + st * 16 + l15;
        int kc2 = kr < 0 ? 0 : (kr > SEQ - 1 ? SEQ - 1 : kr);
        const bf16* kp = khead + (size_t)kc2 * 64 + quad * 8;
        bf16x8 b0 = load8(kp), b1 = load8(kp + 32);
        floatx4 acc = {};
        acc = mfma32(aq0, b0, acc);
        acc = mfma32(aq1, b1, acc);
        s[st] = acc;
    }

    // issue first V fragment batch early; latency hides under softmax VALU
    const bf16* vbase = vhead + (ptrdiff_t)l15 * SEQ + (ws + quad * 8);
    bf16x8 vf[4];
#pragma unroll
    for (int dt = 0; dt < 4; ++dt)
        vf[dt] = load8(vbase + (ptrdiff_t)dt * 16 * SEQ);

    // mask + one-shot softmax; row = quad*4+r, key = ws + 16*st + l15
#pragma unroll
    for (int r = 0; r < 4; ++r) {
        int row = quad * 4 + r;
        float mx = -INFINITY;
#pragma unroll
        for (int st = 0; st < 9; ++st) {
            int j = st * 16 + l15;
            int gk = ws + j;
            bool ok = (j >= row) && (j <= 128 + row) && (gk >= 0) && (gk < SEQ);
            float v = ok ? s[st][r] * 0.125f : -1e30f;
            s[st][r] = v;
            mx = fmaxf(mx, v);
        }
        mx = fmaxf(mx, __shfl_xor(mx, 1));
        mx = fmaxf(mx, __shfl_xor(mx, 2));
        mx = fmaxf(mx, __shfl_xor(mx, 4));
        mx = fmaxf(mx, __shfl_xor(mx, 8));
        float sum = 0.f;
#pragma unroll
        for (int st = 0; st < 9; ++st) {
            float p = __expf(s[st][r] - mx);
            s[st][r] = p;
            sum += p;
        }
        sum += __shfl_xor(sum, 1);
        sum += __shfl_xor(sum, 2);
        sum += __shfl_xor(sum, 4);
        sum += __shfl_xor(sum, 8);
        lred[wave][row] = sum;   // wave-private slot, wave-ordered LDS
    }

    // PV, operand-swapped: a = V^T frag straight from global, b = P frag.
    floatx4 ot[4] = {};
#pragma unroll
    for (int kc = 0; kc < 5; ++kc) {
#pragma unroll
        for (int r = 0; r < 4; ++r) {
            int row = quad * 4 + r;
            Pc[wave][row][l15] = (bf16)s[2 * kc][r];
            Pc[wave][row][16 + l15] = (kc < 4) ? (bf16)s[2 * kc + 1][r] : (bf16)0.f;
        }
        bf16x8 pb = load8(&Pc[wave][l15][quad * 8]);
        bf16x8 vcur[4];
#pragma unroll
        for (int dt = 0; dt < 4; ++dt) vcur[dt] = vf[dt];
        if (kc < 4) {
#pragma unroll
            for (int dt = 0; dt < 4; ++dt)
                vf[dt] = load8(vbase + (ptrdiff_t)dt * 16 * SEQ + (kc + 1) * 32);
        }
        __builtin_amdgcn_s_setprio(1);
#pragma unroll
        for (int dt = 0; dt < 4; ++dt) ot[dt] = mfma32(vcur[dt], pb, ot[dt]);
        __builtin_amdgcn_s_setprio(0);
    }

    float linv = 1.0f / lred[wave][l15];
#pragma unroll
    for (int dt = 0; dt < 4; ++dt) {
        bf16x4 o4;
#pragma unroll
        for (int r = 0; r < 4; ++r) o4[r] = (bf16)(ot[dt][r] * linv);
        *(bf16x4*)(ctx + (size_t)qrow * DM + hoff + dt * 16 + quad * 4) = o4;
    }
}

extern "C" void kernel_launch(void* const* d_in, const int* in_sizes, int n_in,
                              void* d_out, int out_size, void* d_ws, size_t ws_size,
                              hipStream_t stream) {
    const float* x  = (const float*)d_in[0];
    const float* Wq = (const float*)d_in[1];
    const float* bq = (const float*)d_in[2];
    const float* Wk = (const float*)d_in[3];
    const float* bk = (const float*)d_in[4];
    const float* Wv = (const float*)d_in[5];
    const float* bv = (const float*)d_in[6];
    const float* Wo = (const float*)d_in[7];
    const float* bo = (const float*)d_in[8];
    float* out = (float*)d_out;

    const size_t XN = (size_t)SEQ * DM;
    const size_t WN = (size_t)DM * DM;

    bf16* xb    = (bf16*)d_ws;            // XN ; reused as ctx after QKV GEMM
    bf16* Wcat  = xb + XN;                // 3*WN
    bf16* Wob   = Wcat + 3 * WN;          // WN
    bf16* Qh    = Wob + WN;               // XN
    bf16* Kh    = Qh + XN;                // XN
    bf16* VtRaw = Kh + XN;                // XN + 2*GUARD + 128
    bf16* Vtb   = VtRaw + GUARD;
    float* bcat = (float*)(VtRaw + XN + 2 * GUARD + 128);  // 3072 fp32
    bf16* ctx   = xb;                     // alias: xb dead after QKV GEMM

    prep_kernel<<<4097, 256, 0, stream>>>(x, Wq, Wk, Wv, Wo, bq, bk, bv,
                                          xb, Wcat, Wob, bcat);

    gemm_qkv_kernel<<<dim3(SEQ / 128, 24), 256, 0, stream>>>(
        xb, Wcat, bcat, Qh, Kh, Vtb);

    swattn_kernel<<<dim3(SEQ / 64, NH), 256, 0, stream>>>(Qh, Kh, Vtb, ctx);

    gemm_out_kernel<<<dim3(SEQ / 128, DM / 128), 256, 0, stream>>>(
        ctx, Wob, bo, out);
}

// Round 3
// 160.119 us; speedup vs baseline: 1.0327x; 1.0327x over previous
//
#include <hip/hip_runtime.h>
#include <type_traits>

typedef __bf16 bf16;
typedef __bf16 bf16x8 __attribute__((ext_vector_type(8)));
typedef __bf16 bf16x4 __attribute__((ext_vector_type(4)));
typedef float floatx4 __attribute__((ext_vector_type(4)));

#define SEQ 4096
#define DM 1024
#define NH 16
#define HD 64
#define GUARD 64

__device__ __forceinline__ floatx4 mfma32(bf16x8 a, bf16x8 b, floatx4 c) {
    return __builtin_amdgcn_mfma_f32_16x16x32_bf16(a, b, c, 0, 0, 0);
}

__device__ __forceinline__ bf16x8 load8(const bf16* p) {
    return *(const bf16x8*)p;
}

__device__ __forceinline__ void async_ld16(const bf16* g, bf16* l) {
    __builtin_amdgcn_global_load_lds(
        (const __attribute__((address_space(1))) unsigned int*)g,
        (__attribute__((address_space(3))) unsigned int*)l,
        16, 0, 0);
}

// fused prep: cast x, Wq,Wk,Wv,Wo to bf16; concat biases to fp32 bcat.
__global__ __launch_bounds__(256) void prep_kernel(
    const float* __restrict__ x,  const float* __restrict__ Wq,
    const float* __restrict__ Wk, const float* __restrict__ Wv,
    const float* __restrict__ Wo, const float* __restrict__ bq,
    const float* __restrict__ bk, const float* __restrict__ bv,
    bf16* __restrict__ xb, bf16* __restrict__ Wcat,
    bf16* __restrict__ Wob, float* __restrict__ bcat)
{
    const int WN8 = 131072;           // (1024*1024)/8
    const int XN8 = 524288;           // (4096*1024)/8
    int b = blockIdx.x;
    if (b == 4096) {
        for (int k = threadIdx.x; k < 3 * DM; k += 256)
            bcat[k] = k < DM ? bq[k] : (k < 2 * DM ? bk[k - DM] : bv[k - 2 * DM]);
        return;
    }
    int c = b * 256 + threadIdx.x;
    const float* src; bf16* dst;
    if (c < XN8)              { src = x;  dst = xb; }
    else if (c < XN8 + WN8)   { src = Wq; dst = Wcat;                 c -= XN8; }
    else if (c < XN8 + 2*WN8) { src = Wk; dst = Wcat + (size_t)DM*DM;     c -= XN8 + WN8; }
    else if (c < XN8 + 3*WN8) { src = Wv; dst = Wcat + (size_t)2*DM*DM;   c -= XN8 + 2*WN8; }
    else                      { src = Wo; dst = Wob;                  c -= XN8 + 3*WN8; }
    float4 a = ((const float4*)src)[2 * c], d2 = ((const float4*)src)[2 * c + 1];
    bf16x8 o;
    o[0] = (bf16)a.x;  o[1] = (bf16)a.y;  o[2] = (bf16)a.z;  o[3] = (bf16)a.w;
    o[4] = (bf16)d2.x; o[5] = (bf16)d2.y; o[6] = (bf16)d2.z; o[7] = (bf16)d2.w;
    *(bf16x8*)(dst + 8 * (size_t)c) = o;
}

// ---- QKV projection GEMM: [4096,1024] @ [3072,1024]^T, head-major outputs.
// BM=128, BN=128, BK=64, XOR-swizzled LDS (0 bank conflicts, verified r6).
// launch_bounds(256,3): cap regs at 170 so 3 blocks/CU are resident.
// r9: reverted to the prior-session-proven block mapping (r7 remap was
// neutral-to-negative drift across R1/R2).
__global__ __launch_bounds__(256, 3) void gemm_qkv_kernel(
    const bf16* __restrict__ A,      // xb [4096][1024]
    const bf16* __restrict__ B,      // Wcat [3072][1024]
    const float* __restrict__ bias,  // bcat [3072]
    bf16* __restrict__ Qh, bf16* __restrict__ Kh, bf16* __restrict__ Vt)
{
    constexpr int K = DM;
    __shared__ bf16 As[128 * 64];
    __shared__ bf16 Bs[128 * 64];

    const int tid  = threadIdx.x;
    const int wave = tid >> 6;
    const int lane = tid & 63;
    const int l15  = lane & 15;
    const int quad = lane >> 4;
    const int m0 = blockIdx.x * 128;
    const int n0 = blockIdx.y * 128;
    const int wm = (wave & 1) * 64;
    const int wn = (wave >> 1) * 64;

    // staging: chunk = 8 rows x 64 cols (1024B). lane -> (row lane>>3,
    // LDS slot lane&7); global col chunk gc = (slot - row)&7  [XOR swizzle]
    const int lr = lane >> 3;
    const int gc = ((lane & 7) - lr) & 7;

    const bf16* aptr[4]; bf16* alds[4];
    const bf16* bptr[4]; bf16* blds[4];
#pragma unroll
    for (int i = 0; i < 4; ++i) {
        int ci = wave + 4 * i;
        aptr[i] = A + (size_t)(m0 + ci * 8 + lr) * K + gc * 8;
        alds[i] = As + ci * 512;
        bptr[i] = B + (size_t)(n0 + ci * 8 + lr) * K + gc * 8;
        blds[i] = Bs + ci * 512;
    }

    floatx4 acc[4][4] = {};
    const int sw0 = (quad + (l15 & 7)) & 7;   // swizzle base for frag reads
    const bool qk = (n0 < 2 * DM);

    auto kloop = [&](auto swtag) {
        constexpr bool SW = decltype(swtag)::value;
        for (int k0 = 0; k0 < K; k0 += 64) {
            __syncthreads();
#pragma unroll
            for (int i = 0; i < 4; ++i) async_ld16(aptr[i] + k0, alds[i]);
#pragma unroll
            for (int i = 0; i < 4; ++i) async_ld16(bptr[i] + k0, blds[i]);
            __syncthreads();
#pragma unroll
            for (int h = 0; h < 2; ++h) {
                const int so = ((sw0 + 4 * h) & 7) * 8;
                bf16x8 af[4], bfr[4];
#pragma unroll
                for (int i = 0; i < 4; ++i)
                    af[i] = load8(As + (wm + i * 16 + l15) * 64 + so);
#pragma unroll
                for (int j = 0; j < 4; ++j)
                    bfr[j] = load8(Bs + (wn + j * 16 + l15) * 64 + so);
#pragma unroll
                for (int i = 0; i < 4; ++i)
#pragma unroll
                    for (int j = 0; j < 4; ++j)
                        acc[i][j] = SW ? mfma32(bfr[j], af[i], acc[i][j])
                                       : mfma32(af[i], bfr[j], acc[i][j]);
            }
        }
    };
    if (qk) kloop(std::true_type{}); else kloop(std::false_type{});

    const int nb = n0 + wn;   // multiple of 64
    if (qk) {
        // swapped: lane holds 4 consecutive out-cols (head dims) for row s
        bf16* dst = (nb < DM) ? Qh : Kh;
        const int hh = ((nb < DM) ? nb : nb - DM) >> 6;
#pragma unroll
        for (int i = 0; i < 4; ++i) {
            int s = m0 + wm + i * 16 + l15;
            bf16* row = dst + ((size_t)hh * SEQ + s) * 64;
#pragma unroll
            for (int j = 0; j < 4; ++j) {
                int d4 = j * 16 + quad * 4;
                float4 bv = *(const float4*)(bias + nb + d4);
                bf16x4 o = {(bf16)(acc[i][j][0] + bv.x), (bf16)(acc[i][j][1] + bv.y),
                            (bf16)(acc[i][j][2] + bv.z), (bf16)(acc[i][j][3] + bv.w)};
                *(bf16x4*)(row + d4) = o;
            }
        }
    } else {
        // non-swapped: lane holds 4 consecutive s for out-col -> V^T rows
#pragma unroll
        for (int j = 0; j < 4; ++j) {
            int vrow = (nb - 2 * DM) + j * 16 + l15;     // h*64+d, 0..1023
            float bvs = bias[nb + j * 16 + l15];
            bf16* row = Vt + (size_t)vrow * SEQ;
#pragma unroll
            for (int i = 0; i < 4; ++i) {
                int s4 = m0 + wm + i * 16 + quad * 4;
                bf16x4 o = {(bf16)(acc[i][j][0] + bvs), (bf16)(acc[i][j][1] + bvs),
                            (bf16)(acc[i][j][2] + bvs), (bf16)(acc[i][j][3] + bvs)};
                *(bf16x4*)(row + s4) = o;
            }
        }
    }
}

// ---- out-projection GEMM (swapped, row-major fp32 out), BM=64, BK=64.
// r9: reverted to BM=64 / grid 512 (2 blocks/CU). The r8 128x128 variant
// at grid 256 = 1 block/CU measured equal (naked barrier-drain cancels
// the better MFMA:ds ratio) — keep the prior-session-proven version.
template <int BM, typename TOUT>
__global__ __launch_bounds__(256, 4) void gemm_sw_kernel(
    const bf16* __restrict__ A, const bf16* __restrict__ B,
    const float* __restrict__ bias, TOUT* __restrict__ C,
    int M, int N, int K)
{
    constexpr int MI = BM / 32;
    __shared__ bf16 As[BM * 64];
    __shared__ bf16 Bs[128 * 64];

    const int tid  = threadIdx.x;
    const int wave = tid >> 6;
    const int lane = tid & 63;
    const int l15  = lane & 15;
    const int quad = lane >> 4;
    const int m0 = blockIdx.x * BM;
    const int n0 = blockIdx.y * 128;
    const int wm = (wave & 1) * (BM / 2);
    const int wn = (wave >> 1) * 64;

    const int lr = lane >> 3;
    const int gc = ((lane & 7) - lr) & 7;

    const bf16* aptr[MI]; bf16* alds[MI];
    const bf16* bptr[4];  bf16* blds[4];
#pragma unroll
    for (int i = 0; i < MI; ++i) {
        int ci = wave + 4 * i;
        aptr[i] = A + (size_t)(m0 + ci * 8 + lr) * K + gc * 8;
        alds[i] = As + ci * 512;
    }
#pragma unroll
    for (int j = 0; j < 4; ++j) {
        int cj = wave + 4 * j;
        bptr[j] = B + (size_t)(n0 + cj * 8 + lr) * K + gc * 8;
        blds[j] = Bs + cj * 512;
    }

    floatx4 acc[MI][4] = {};
    const int sw0 = (quad + (l15 & 7)) & 7;

    for (int k0 = 0; k0 < K; k0 += 64) {
        __syncthreads();
#pragma unroll
        for (int i = 0; i < MI; ++i) async_ld16(aptr[i] + k0, alds[i]);
#pragma unroll
        for (int j = 0; j < 4; ++j) async_ld16(bptr[j] + k0, blds[j]);
        __syncthreads();
#pragma unroll
        for (int h = 0; h < 2; ++h) {
            const int so = ((sw0 + 4 * h) & 7) * 8;
            bf16x8 af[MI], bfr[4];
#pragma unroll
            for (int i = 0; i < MI; ++i)
                af[i] = load8(As + (wm + i * 16 + l15) * 64 + so);
#pragma unroll
            for (int j = 0; j < 4; ++j)
                bfr[j] = load8(Bs + (wn + j * 16 + l15) * 64 + so);
#pragma unroll
            for (int i = 0; i < MI; ++i)
#pragma unroll
                for (int j = 0; j < 4; ++j)
                    acc[i][j] = mfma32(bfr[j], af[i], acc[i][j]);
        }
    }

#pragma unroll
    for (int i = 0; i < MI; ++i) {
        int xm = m0 + wm + i * 16 + l15;
#pragma unroll
        for (int j = 0; j < 4; ++j) {
            int cn = n0 + wn + j * 16 + quad * 4;
            float4 bv = *(const float4*)(bias + cn);
            float v0 = acc[i][j][0] + bv.x;
            float v1 = acc[i][j][1] + bv.y;
            float v2 = acc[i][j][2] + bv.z;
            float v3 = acc[i][j][3] + bv.w;
            if constexpr (sizeof(TOUT) == 2) {
                bf16x4 o = {(bf16)v0, (bf16)v1, (bf16)v2, (bf16)v3};
                *(bf16x4*)((bf16*)C + (size_t)xm * N + cn) = o;
            } else {
                float4 o = {v0, v1, v2, v3};
                *(float4*)((float*)C + (size_t)xm * N + cn) = o;
            }
        }
    }
}

// ---- sliding-window attention, head-major inputs, zero barriers.
// Qh,Kh: [h][s][64]; Vt: [h*64+d][SEQ] (base has 64-elem guard each side).
// r9: reverted to the prior-session-proven version (r7's remap, V-prefetch
// and setprio were all within-noise; removing to eliminate drift).
__global__ __launch_bounds__(256) void swattn_kernel(
    const bf16* __restrict__ Qh, const bf16* __restrict__ Kh,
    const bf16* __restrict__ Vt, bf16* __restrict__ ctx)
{
    __shared__ bf16 Pc[4][16][40];
    __shared__ float lred[4][16];

    const int tid  = threadIdx.x;
    const int wave = tid >> 6;
    const int lane = tid & 63;
    const int l15  = lane & 15;
    const int quad = lane >> 4;
    const int q0   = blockIdx.x * 64;
    const int h    = blockIdx.y;
    const int hoff = h * HD;

    const bf16* qhead = Qh + (size_t)h * SEQ * 64;
    const bf16* khead = Kh + (size_t)h * SEQ * 64;
    const bf16* vhead = Vt + (size_t)hoff * SEQ;

    const int qrow = q0 + wave * 16 + l15;
    bf16x8 aq0 = load8(qhead + (size_t)qrow * 64 + quad * 8);
    bf16x8 aq1 = load8(qhead + (size_t)qrow * 64 + quad * 8 + 32);

    const int ws = q0 - 64 + wave * 16;   // wave window start (global key)
    floatx4 s[9];
#pragma unroll
    for (int st = 0; st < 9; ++st) {
        int kr = ws + st * 16 + l15;
        int kc2 = kr < 0 ? 0 : (kr > SEQ - 1 ? SEQ - 1 : kr);
        const bf16* kp = khead + (size_t)kc2 * 64 + quad * 8;
        bf16x8 b0 = load8(kp), b1 = load8(kp + 32);
        floatx4 acc = {};
        acc = mfma32(aq0, b0, acc);
        acc = mfma32(aq1, b1, acc);
        s[st] = acc;
    }

    // mask + one-shot softmax; row = quad*4+r, key = ws + 16*st + l15
#pragma unroll
    for (int r = 0; r < 4; ++r) {
        int row = quad * 4 + r;
        float mx = -INFINITY;
#pragma unroll
        for (int st = 0; st < 9; ++st) {
            int j = st * 16 + l15;
            int gk = ws + j;
            bool ok = (j >= row) && (j <= 128 + row) && (gk >= 0) && (gk < SEQ);
            float v = ok ? s[st][r] * 0.125f : -1e30f;
            s[st][r] = v;
            mx = fmaxf(mx, v);
        }
        mx = fmaxf(mx, __shfl_xor(mx, 1));
        mx = fmaxf(mx, __shfl_xor(mx, 2));
        mx = fmaxf(mx, __shfl_xor(mx, 4));
        mx = fmaxf(mx, __shfl_xor(mx, 8));
        float sum = 0.f;
#pragma unroll
        for (int st = 0; st < 9; ++st) {
            float p = __expf(s[st][r] - mx);
            s[st][r] = p;
            sum += p;
        }
        sum += __shfl_xor(sum, 1);
        sum += __shfl_xor(sum, 2);
        sum += __shfl_xor(sum, 4);
        sum += __shfl_xor(sum, 8);
        lred[wave][row] = sum;   // wave-private slot, wave-ordered LDS
    }

    // PV, operand-swapped: a = V^T frag straight from global, b = P frag.
    floatx4 ot[4] = {};
#pragma unroll
    for (int kc = 0; kc < 5; ++kc) {
#pragma unroll
        for (int r = 0; r < 4; ++r) {
            int row = quad * 4 + r;
            Pc[wave][row][l15] = (bf16)s[2 * kc][r];
            Pc[wave][row][16 + l15] = (kc < 4) ? (bf16)s[2 * kc + 1][r] : (bf16)0.f;
        }
        bf16x8 pb = load8(&Pc[wave][l15][quad * 8]);
#pragma unroll
        for (int dt = 0; dt < 4; ++dt) {
            const bf16* vp = vhead + (ptrdiff_t)(dt * 16 + l15) * SEQ
                                   + (ptrdiff_t)(ws + kc * 32 + quad * 8);
            ot[dt] = mfma32(load8(vp), pb, ot[dt]);
        }
    }

    float linv = 1.0f / lred[wave][l15];
#pragma unroll
    for (int dt = 0; dt < 4; ++dt) {
        bf16x4 o4;
#pragma unroll
        for (int r = 0; r < 4; ++r) o4[r] = (bf16)(ot[dt][r] * linv);
        *(bf16x4*)(ctx + (size_t)qrow * DM + hoff + dt * 16 + quad * 4) = o4;
    }
}

extern "C" void kernel_launch(void* const* d_in, const int* in_sizes, int n_in,
                              void* d_out, int out_size, void* d_ws, size_t ws_size,
                              hipStream_t stream) {
    const float* x  = (const float*)d_in[0];
    const float* Wq = (const float*)d_in[1];
    const float* bq = (const float*)d_in[2];
    const float* Wk = (const float*)d_in[3];
    const float* bk = (const float*)d_in[4];
    const float* Wv = (const float*)d_in[5];
    const float* bv = (const float*)d_in[6];
    const float* Wo = (const float*)d_in[7];
    const float* bo = (const float*)d_in[8];
    float* out = (float*)d_out;

    const size_t XN = (size_t)SEQ * DM;
    const size_t WN = (size_t)DM * DM;

    bf16* xb    = (bf16*)d_ws;            // XN ; reused as ctx after QKV GEMM
    bf16* Wcat  = xb + XN;                // 3*WN
    bf16* Wob   = Wcat + 3 * WN;          // WN
    bf16* Qh    = Wob + WN;               // XN
    bf16* Kh    = Qh + XN;                // XN
    bf16* VtRaw = Kh + XN;                // XN + 2*GUARD + 128
    bf16* Vtb   = VtRaw + GUARD;
    float* bcat = (float*)(VtRaw + XN + 2 * GUARD + 128);  // 3072 fp32
    bf16* ctx   = xb;                     // alias: xb dead after QKV GEMM

    prep_kernel<<<4097, 256, 0, stream>>>(x, Wq, Wk, Wv, Wo, bq, bk, bv,
                                          xb, Wcat, Wob, bcat);

    gemm_qkv_kernel<<<dim3(SEQ / 128, 24), 256, 0, stream>>>(
        xb, Wcat, bcat, Qh, Kh, Vtb);

    swattn_kernel<<<dim3(SEQ / 64, NH), 256, 0, stream>>>(Qh, Kh, Vtb, ctx);

    gemm_sw_kernel<64, float><<<dim3(SEQ / 64, DM / 128), 256, 0, stream>>>(
        ctx, Wob, bo, out, SEQ, DM, DM);
}